// Round 4
// baseline (153.132 us; speedup 1.0000x reference)
//
#include <hip/hip_runtime.h>
#include <math.h>

#define N_NODES 50000
#define N_EDGES 600000
#define ALPHA 0.01f
#define NB2 256            // e-streaming blocks in KA
#define NB1 782            // node-GEMM blocks in KA (782*64 >= 50000)
#define KB_GRID 1024
#define KC_GRID 256

__device__ __forceinline__ float leaky(float x) { return x > 0.f ? x : ALPHA * x; }

// ================= KA: fused [e-stream -> dsc] || [node GEMM -> hp, ps, pd] ==========
// blocks [0, NB2): zero w, compute w_em redundantly, dsc[i] = e[i,:] . w_em
// blocks [NB2, NB2+NB1): 64-row tile of h_prime = leaky(h @ Wu); ps/pd scalars
// GEMM role: A-tile (64x132) resident in LDS; B consumed in BK=32 panels,
// next panel prefetched to registers during compute of current panel.
__global__ __launch_bounds__(256) void ka_fused(
        const float* __restrict__ h, const float* __restrict__ Wu,
        const float* __restrict__ a, const float* __restrict__ e,
        const float* __restrict__ W_e, const float* __restrict__ W_m,
        float* __restrict__ hp, float* __restrict__ ps, float* __restrict__ pd,
        float* __restrict__ w, float* __restrict__ dsc) {
    __shared__ float smem[64 * 132 + 32 * 128 + 256];   // A | B-panel | a-vec (51.2 KB)
    float* sh  = smem;                 // 64 x 132 A-tile
    float* swB = smem + 64 * 132;      // 32 x 128 B-panel
    float* sa  = smem + 64 * 132 + 32 * 128;  // a[256]
    int t = threadIdx.x;

    if (blockIdx.x < NB2) {
        // ---- edge-stream role ----
        float* swem = smem;            // reuse LDS
        int gid = blockIdx.x * 256 + t;
        for (int i = gid; i < N_NODES; i += NB2 * 256) w[i] = 0.f;
        if (t < 64) {
            float acc = 0.f;
            const float* row = W_e + t * 128;
            #pragma unroll 8
            for (int k = 0; k < 128; ++k) acc += row[k] * W_m[k];
            swem[t] = acc;
        }
        __syncthreads();
        int lane = t & 63;
        int q = lane & 15;
        int sub = lane >> 4;
        int gw = (blockIdx.x * 256 + t) >> 6;       // global wave id, 0..NB2*4-1
        const int nw = NB2 * 4;
        float4 wv = ((const float4*)swem)[q];
        for (int base = gw * 4; base < N_EDGES; base += nw * 4) {
            int eidx = base + sub;                  // E%4==0 -> in range
            float4 ev = ((const float4*)(e + (size_t)eidx * 64))[q];
            float d = ev.x * wv.x + ev.y * wv.y + ev.z * wv.z + ev.w * wv.w;
            d += __shfl_xor(d, 1);
            d += __shfl_xor(d, 2);
            d += __shfl_xor(d, 4);
            d += __shfl_xor(d, 8);
            if (q == 0) dsc[eidx] = d;
        }
        return;
    }

    // ---- node-GEMM role ----
    int base = (blockIdx.x - NB2) * 64;
    int rl = t >> 5;                   // 0..7
    int c4 = t & 31;                   // 0..31

    if (t < 256) sa[t] = a[t];
    // stage A-tile (64 rows x 128 cols) as float4
    #pragma unroll
    for (int i = 0; i < 8; ++i) {
        int idx = t + i * 256;         // 0..2047
        int row = idx >> 5, c = idx & 31;
        float4 v = make_float4(0.f, 0.f, 0.f, 0.f);
        if (base + row < N_NODES)
            v = ((const float4*)h)[(size_t)(base + row) * 32 + c];
        *(float4*)(sh + row * 132 + c * 4) = v;
    }
    // load B panel 0 into regs
    float4 breg0, breg1, breg2, breg3;
    {
        int i0 = t, i1 = t + 256, i2 = t + 512, i3 = t + 768;
        breg0 = ((const float4*)Wu)[(size_t)((i0 >> 5)) * 32 + (i0 & 31)];
        breg1 = ((const float4*)Wu)[(size_t)((i1 >> 5)) * 32 + (i1 & 31)];
        breg2 = ((const float4*)Wu)[(size_t)((i2 >> 5)) * 32 + (i2 & 31)];
        breg3 = ((const float4*)Wu)[(size_t)((i3 >> 5)) * 32 + (i3 & 31)];
    }
    __syncthreads();
    // write panel 0 to LDS
    ((float4*)swB)[t]       = breg0;
    ((float4*)swB)[t + 256] = breg1;
    ((float4*)swB)[t + 512] = breg2;
    ((float4*)swB)[t + 768] = breg3;
    __syncthreads();

    float acc[8][4];
    #pragma unroll
    for (int j = 0; j < 8; ++j)
        #pragma unroll
        for (int x = 0; x < 4; ++x) acc[j][x] = 0.f;

    #pragma unroll
    for (int p = 0; p < 4; ++p) {
        // prefetch next panel into regs (global, L2-hot)
        if (p < 3) {
            int kbase = (p + 1) * 32;
            int i0 = t, i1 = t + 256, i2 = t + 512, i3 = t + 768;
            breg0 = ((const float4*)Wu)[(size_t)(kbase + (i0 >> 5)) * 32 + (i0 & 31)];
            breg1 = ((const float4*)Wu)[(size_t)(kbase + (i1 >> 5)) * 32 + (i1 & 31)];
            breg2 = ((const float4*)Wu)[(size_t)(kbase + (i2 >> 5)) * 32 + (i2 & 31)];
            breg3 = ((const float4*)Wu)[(size_t)(kbase + (i3 >> 5)) * 32 + (i3 & 31)];
        }
        // compute current panel
        #pragma unroll 4
        for (int kr = 0; kr < 32; ++kr) {
            float4 wv = *(const float4*)(swB + kr * 128 + c4 * 4);
            int kc = p * 32 + kr;
            #pragma unroll
            for (int j = 0; j < 8; ++j) {
                float hv = sh[(rl + 8 * j) * 132 + kc];
                acc[j][0] += hv * wv.x;
                acc[j][1] += hv * wv.y;
                acc[j][2] += hv * wv.z;
                acc[j][3] += hv * wv.w;
            }
        }
        __syncthreads();
        if (p < 3) {
            ((float4*)swB)[t]       = breg0;
            ((float4*)swB)[t + 256] = breg1;
            ((float4*)swB)[t + 512] = breg2;
            ((float4*)swB)[t + 768] = breg3;
            __syncthreads();
        }
    }

    // epilogue: leaky, ps/pd dot-products, writes
    int cb = c4 * 4;
    #pragma unroll
    for (int j = 0; j < 8; ++j) {
        int row = base + rl + 8 * j;
        float4 o;
        o.x = leaky(acc[j][0]);
        o.y = leaky(acc[j][1]);
        o.z = leaky(acc[j][2]);
        o.w = leaky(acc[j][3]);
        float p1 = o.x * sa[cb] + o.y * sa[cb + 1] + o.z * sa[cb + 2] + o.w * sa[cb + 3];
        float p2 = o.x * sa[128 + cb] + o.y * sa[128 + cb + 1] +
                   o.z * sa[128 + cb + 2] + o.w * sa[128 + cb + 3];
        #pragma unroll
        for (int m = 16; m >= 1; m >>= 1) {
            p1 += __shfl_xor(p1, m);
            p2 += __shfl_xor(p2, m);
        }
        if (row < N_NODES) {
            ((float4*)(hp + (size_t)row * 128))[c4] = o;
            if (c4 == 0) { ps[row] = p1; pd[row] = p2; }
        }
    }
}

// ================= KB: per-edge p = exp(sigmoid(ps+pd)*dsc); w[src]+=p; Spart =========
__global__ __launch_bounds__(256) void kb_edge(
        const int* __restrict__ src, const int* __restrict__ dst,
        const float* __restrict__ dsc, const float* __restrict__ ps,
        const float* __restrict__ pd, float* __restrict__ w,
        double* __restrict__ Spart) {
    int t = threadIdx.x;
    int gid = blockIdx.x * 256 + t;
    double sacc = 0.0;
    for (int i = gid; i < N_EDGES; i += KB_GRID * 256) {
        int s = src[i];
        float score = ps[s] + pd[dst[i]];
        float sig = 1.f / (1.f + expf(-score));
        float p = expf(sig * dsc[i]);
        atomicAdd(&w[s], p);
        sacc += (double)p;
    }
    __shared__ double sred[256];
    sred[t] = sacc;
    __syncthreads();
    for (int s2 = 128; s2 > 0; s2 >>= 1) {
        if (t < s2) sred[t] += sred[t + s2];
        __syncthreads();
    }
    if (t == 0) Spart[blockIdx.x] = sred[0];
}

// ================= KC: hgpart[b][col] = sum_rows w[row]*leaky(hp[row][col]) ===========
__global__ __launch_bounds__(256) void kc_hg(
        const float* __restrict__ hp, const float* __restrict__ w,
        double* __restrict__ hgpart) {
    int t = threadIdx.x;
    int col = t & 127;
    int half = t >> 7;
    double acc = 0.0;
    for (int r0 = blockIdx.x * 2; r0 < N_NODES; r0 += KC_GRID * 2) {
        int row = r0 + half;                       // N even
        float wvv = w[row];
        float g = leaky(hp[(size_t)row * 128 + col]);
        acc += (double)(wvv * g);
    }
    __shared__ double sred[256];
    sred[t] = acc;
    __syncthreads();
    if (t < 128) hgpart[blockIdx.x * 128 + t] = sred[t] + sred[t + 128];
}

// ================= KD: reduce S/hg + full MLP in one block ============================
__global__ __launch_bounds__(1024) void kd_tail(
        const double* __restrict__ Spart, const double* __restrict__ hgpart,
        const float* __restrict__ W1, const float* __restrict__ b1,
        const float* __restrict__ W2, const float* __restrict__ b2,
        const float* __restrict__ W3, const float* __restrict__ b3,
        const float* __restrict__ W4, const float* __restrict__ b4,
        float* __restrict__ out) {
    __shared__ double dred[1024];
    __shared__ float fpart[1024];
    __shared__ float hgs[128];
    __shared__ float x1s[512];
    __shared__ float x2s[128];
    __shared__ float x3s[16];
    int t = threadIdx.x;

    dred[t] = Spart[t];                            // KB_GRID == 1024
    __syncthreads();
    for (int st = 512; st > 0; st >>= 1) {
        if (t < st) dred[t] += dred[t + st];
        __syncthreads();
    }
    double S = dred[0];
    __syncthreads();

    {   // hg
        int c = t & 127, g = t >> 7;
        double acc = 0.0;
        #pragma unroll 4
        for (int i = 0; i < 32; ++i)
            acc += hgpart[(size_t)(g * 32 + i) * 128 + c];
        dred[t] = acc;
        __syncthreads();
        if (t < 128) {
            double tot = 0.0;
            #pragma unroll
            for (int g2 = 0; g2 < 8; ++g2) tot += dred[t + 128 * g2];
            hgs[t] = (float)(tot / S);
        }
    }
    __syncthreads();

    {   // L1
        int o = t & 511, g = t >> 9;
        float acc = 0.f;
        #pragma unroll 8
        for (int i = 0; i < 64; ++i) {
            int d = g * 64 + i;
            acc += hgs[d] * W1[d * 512 + o];
        }
        fpart[t] = acc;
        __syncthreads();
        if (t < 512) x1s[t] = fmaxf(fpart[t] + fpart[t + 512] + b1[t], 0.f);
    }
    __syncthreads();

    {   // L2
        int o = t & 127, g = t >> 7;
        float acc = 0.f;
        #pragma unroll 8
        for (int i = 0; i < 64; ++i) {
            int k = g * 64 + i;
            acc += x1s[k] * W2[k * 128 + o];
        }
        fpart[t] = acc;
        __syncthreads();
        if (t < 128) {
            float s2 = b2[t];
            #pragma unroll
            for (int g2 = 0; g2 < 8; ++g2) s2 += fpart[t + 128 * g2];
            x2s[t] = fmaxf(s2, 0.f);
        }
    }
    __syncthreads();

    {   // L3
        if (t < 256) {
            int o = t & 15, g = t >> 4;
            float acc = 0.f;
            #pragma unroll
            for (int i = 0; i < 8; ++i) {
                int k = g * 8 + i;
                acc += x2s[k] * W3[k * 16 + o];
            }
            fpart[t] = acc;
        }
        __syncthreads();
        if (t < 16) {
            float s3 = b3[t];
            #pragma unroll
            for (int g2 = 0; g2 < 16; ++g2) s3 += fpart[t + 16 * g2];
            x3s[t] = fmaxf(s3, 0.f);
        }
    }
    __syncthreads();

    if (t == 0) {
        float acc = b4[0];
        #pragma unroll
        for (int k = 0; k < 16; ++k) acc += x3s[k] * W4[k];
        out[0] = acc;
    }
}

extern "C" void kernel_launch(void* const* d_in, const int* in_sizes, int n_in,
                              void* d_out, int out_size, void* d_ws, size_t ws_size,
                              hipStream_t stream) {
    const float* h   = (const float*)d_in[0];
    const float* e   = (const float*)d_in[1];
    const int*   src = (const int*)d_in[2];
    const int*   dst = (const int*)d_in[3];
    const float* W_u = (const float*)d_in[4];
    const float* W_e = (const float*)d_in[5];
    const float* a   = (const float*)d_in[6];
    const float* W_m = (const float*)d_in[7];
    const float* W1  = (const float*)d_in[8];
    const float* b1  = (const float*)d_in[9];
    const float* W2  = (const float*)d_in[10];
    const float* b2  = (const float*)d_in[11];
    const float* W3  = (const float*)d_in[12];
    const float* b3  = (const float*)d_in[13];
    const float* W4  = (const float*)d_in[14];
    const float* b4  = (const float*)d_in[15];
    float* out = (float*)d_out;

    char* ws = (char*)d_ws;
    float*  hp    = (float*)(ws);                     // 50000*128 f
    float*  ps    = (float*)(ws + 25600000);          // 50000 f
    float*  pd    = (float*)(ws + 25800000);          // 50000 f
    float*  w     = (float*)(ws + 26000000);          // 50000 f
    float*  dsc   = (float*)(ws + 26200000);          // 600000 f
    double* Spart = (double*)(ws + 28600000);         // 1024 d
    double* hgpart= (double*)(ws + 28608192);         // 256*128 d -> ends 28,870,336

    hipLaunchKernelGGL(ka_fused, dim3(NB2 + NB1), dim3(256), 0, stream,
                       h, W_u, a, e, W_e, W_m, hp, ps, pd, w, dsc);
    hipLaunchKernelGGL(kb_edge, dim3(KB_GRID), dim3(256), 0, stream,
                       src, dst, dsc, ps, pd, w, Spart);
    hipLaunchKernelGGL(kc_hg, dim3(KC_GRID), dim3(256), 0, stream, hp, w, hgpart);
    hipLaunchKernelGGL(kd_tail, dim3(1), dim3(1024), 0, stream,
                       Spart, hgpart, W1, b1, W2, b2, W3, b3, W4, b4, out);
}

// Round 5
// 129.738 us; speedup vs baseline: 1.1803x; 1.1803x over previous
//
#include <hip/hip_runtime.h>
#include <math.h>

#define N_NODES 50000
#define N_EDGES 600000
#define ALPHA 0.01f
#define NB2 512            // e-streaming blocks in KA
#define NB1 782            // node-GEMM blocks in KA (782*64 = 50048 >= 50000)
#define KB_GRID 1024
#define KC_GRID 256

typedef unsigned short u16;
typedef unsigned int u32;
using short8 = __attribute__((ext_vector_type(8))) short;
using f32x4  = __attribute__((ext_vector_type(4))) float;

__device__ __forceinline__ float leaky(float x) { return x > 0.f ? x : ALPHA * x; }

// round-to-nearest fp32 -> bf16 bits
__device__ __forceinline__ u16 f2bf_rn(float x) {
    u32 u = __float_as_uint(x);
    u32 r = (u + 0x7FFFu + ((u >> 16) & 1u)) >> 16;
    return (u16)r;
}
__device__ __forceinline__ float bf2f(u16 b) { return __uint_as_float(((u32)b) << 16); }

// ================= KP: pack W_u into MFMA B-fragment layout (bf16 hi/lo) =============
// Bfrag index: ((nt*4+kt)*64 + lane)*8 + j  holds Wu[kt*32 + (lane>>4)*8 + j][nt*16 + (lane&15)]
__global__ __launch_bounds__(256) void kp_pack(const float* __restrict__ Wu,
                                               u16* __restrict__ Bhi, u16* __restrict__ Blo) {
    int g = blockIdx.x * 256 + threadIdx.x;     // 0..2047
    if (g >= 2048) return;
    int f = g >> 6;                              // nt*4+kt, 0..31
    int L = g & 63;
    int nt = f >> 2, kt = f & 3;
    int kbase = kt * 32 + (L >> 4) * 8;
    int col = nt * 16 + (L & 15);
    #pragma unroll
    for (int j = 0; j < 8; ++j) {
        float x = Wu[(size_t)(kbase + j) * 128 + col];
        u16 hi = f2bf_rn(x);
        u16 lo = f2bf_rn(x - bf2f(hi));
        Bhi[(size_t)g * 8 + j] = hi;
        Blo[(size_t)g * 8 + j] = lo;
    }
}

// ================= KA: fused [e-stream -> dsc] || [MFMA node GEMM -> hp, ps, pd] ======
__global__ __launch_bounds__(256) void ka_fused(
        const float* __restrict__ h, const float* __restrict__ a,
        const float* __restrict__ e, const float* __restrict__ W_e,
        const float* __restrict__ W_m, const u16* __restrict__ Bhi,
        const u16* __restrict__ Blo,
        float* __restrict__ hp, float* __restrict__ ps, float* __restrict__ pd,
        float* __restrict__ w, float* __restrict__ dsc) {
    __shared__ u16 sAhi[64 * 128];
    __shared__ u16 sAlo[64 * 128];
    __shared__ float sav[256];
    __shared__ float swem[64];
    int t = threadIdx.x;

    if (blockIdx.x < NB2) {
        // ---- edge-stream role (R3 geometry) ----
        int gid = blockIdx.x * 256 + t;
        for (int i = gid; i < N_NODES; i += NB2 * 256) w[i] = 0.f;
        if (t < 64) {
            float acc = 0.f;
            const float* row = W_e + t * 128;
            #pragma unroll 8
            for (int k = 0; k < 128; ++k) acc += row[k] * W_m[k];
            swem[t] = acc;
        }
        __syncthreads();
        int lane = t & 63;
        int q = lane & 15;
        int sub = lane >> 4;
        int gw = (blockIdx.x * 256 + t) >> 6;
        const int nw = NB2 * 4;
        float4 wv = ((const float4*)swem)[q];
        for (int base = gw * 4; base < N_EDGES; base += nw * 4) {
            int eidx = base + sub;                  // E%4==0 -> in range
            float4 ev = ((const float4*)(e + (size_t)eidx * 64))[q];
            float d = ev.x * wv.x + ev.y * wv.y + ev.z * wv.z + ev.w * wv.w;
            d += __shfl_xor(d, 1);
            d += __shfl_xor(d, 2);
            d += __shfl_xor(d, 4);
            d += __shfl_xor(d, 8);
            if (q == 0) dsc[eidx] = d;
        }
        return;
    }

    // ---- MFMA node-GEMM role: 64 rows/block ----
    int base = (blockIdx.x - NB2) * 64;
    if (t < 256) sav[t] = a[t];

    // stage h-tile as bf16 hi/lo into swizzled LDS (convert from global inline)
    #pragma unroll
    for (int it = 0; it < 8; ++it) {
        int i = t + it * 256;                      // 0..2047
        int row = i >> 5, c4 = i & 31;
        float4 v = make_float4(0.f, 0.f, 0.f, 0.f);
        if (base + row < N_NODES)
            v = ((const float4*)h)[(size_t)(base + row) * 32 + c4];
        u16 h0 = f2bf_rn(v.x), h1 = f2bf_rn(v.y), h2 = f2bf_rn(v.z), h3 = f2bf_rn(v.w);
        u16 l0 = f2bf_rn(v.x - bf2f(h0)), l1 = f2bf_rn(v.y - bf2f(h1));
        u16 l2 = f2bf_rn(v.z - bf2f(h2)), l3 = f2bf_rn(v.w - bf2f(h3));
        uint2 whi = make_uint2((u32)h0 | ((u32)h1 << 16), (u32)h2 | ((u32)h3 << 16));
        uint2 wlo = make_uint2((u32)l0 | ((u32)l1 << 16), (u32)l2 | ((u32)l3 << 16));
        int idx = (row * 128 + c4 * 4) ^ ((row & 7) << 3);   // ushort idx, swizzled
        *(uint2*)(sAhi + idx) = whi;
        *(uint2*)(sAlo + idx) = wlo;
    }
    __syncthreads();

    int lane = t & 63;
    int wv = t >> 6;                               // wave 0..3 -> local rows wv*16..+15
    int khalf = lane >> 4;                         // 0..3
    int l15 = lane & 15;

    // load 8 A-fragments (4 k-tiles x hi/lo) into registers
    short8 ahi[4], alo[4];
    {
        int rloc = wv * 16 + l15;
        #pragma unroll
        for (int kt = 0; kt < 4; ++kt) {
            int idx = (rloc * 128 + kt * 32 + khalf * 8) ^ ((rloc & 7) << 3);
            ahi[kt] = *(const short8*)(sAhi + idx);
            alo[kt] = *(const short8*)(sAlo + idx);
        }
    }

    float psum1[4] = {0.f, 0.f, 0.f, 0.f};
    float psum2[4] = {0.f, 0.f, 0.f, 0.f};

    #pragma unroll
    for (int nt = 0; nt < 8; ++nt) {
        f32x4 acc = {0.f, 0.f, 0.f, 0.f};
        #pragma unroll
        for (int kt = 0; kt < 4; ++kt) {
            size_t bi = ((size_t)(nt * 4 + kt) * 64 + lane) * 8;
            short8 bhi = *(const short8*)(Bhi + bi);
            short8 blo = *(const short8*)(Blo + bi);
            acc = __builtin_amdgcn_mfma_f32_16x16x32_bf16(ahi[kt], bhi, acc, 0, 0, 0);
            acc = __builtin_amdgcn_mfma_f32_16x16x32_bf16(alo[kt], bhi, acc, 0, 0, 0);
            acc = __builtin_amdgcn_mfma_f32_16x16x32_bf16(ahi[kt], blo, acc, 0, 0, 0);
        }
        // epilogue for this 16-col tile
        int colg = nt * 16 + l15;
        float a1 = sav[colg], a2 = sav[128 + colg];
        #pragma unroll
        for (int r = 0; r < 4; ++r) {
            float o = leaky(acc[r]);
            int rloc = wv * 16 + khalf * 4 + r;    // C/D row = (lane>>4)*4 + reg
            int row = base + rloc;
            if (row < N_NODES) hp[(size_t)row * 128 + colg] = o;
            psum1[r] += o * a1;
            psum2[r] += o * a2;
        }
    }

    // ps/pd: reduce across the 16-lane column group
    #pragma unroll
    for (int r = 0; r < 4; ++r) {
        float p1 = psum1[r], p2 = psum2[r];
        #pragma unroll
        for (int m = 8; m >= 1; m >>= 1) {
            p1 += __shfl_xor(p1, m);
            p2 += __shfl_xor(p2, m);
        }
        if (l15 == 0) {
            int row = base + wv * 16 + khalf * 4 + r;
            if (row < N_NODES) { ps[row] = p1; pd[row] = p2; }
        }
    }
}

// ================= KB: per-edge p = exp(sigmoid(ps+pd)*dsc); w[src]+=p; Spart =========
__global__ __launch_bounds__(256) void kb_edge(
        const int* __restrict__ src, const int* __restrict__ dst,
        const float* __restrict__ dsc, const float* __restrict__ ps,
        const float* __restrict__ pd, float* __restrict__ w,
        double* __restrict__ Spart) {
    int t = threadIdx.x;
    int gid = blockIdx.x * 256 + t;
    double sacc = 0.0;
    for (int i = gid; i < N_EDGES; i += KB_GRID * 256) {
        int s = src[i];
        float score = ps[s] + pd[dst[i]];
        float sig = 1.f / (1.f + expf(-score));
        float p = expf(sig * dsc[i]);
        atomicAdd(&w[s], p);
        sacc += (double)p;
    }
    __shared__ double sred[256];
    sred[t] = sacc;
    __syncthreads();
    for (int s2 = 128; s2 > 0; s2 >>= 1) {
        if (t < s2) sred[t] += sred[t + s2];
        __syncthreads();
    }
    if (t == 0) Spart[blockIdx.x] = sred[0];
}

// ================= KC: hgpart[b][col] = sum_rows w[row]*leaky(hp[row][col]) ===========
__global__ __launch_bounds__(256) void kc_hg(
        const float* __restrict__ hp, const float* __restrict__ w,
        double* __restrict__ hgpart) {
    int t = threadIdx.x;
    int col = t & 127;
    int half = t >> 7;
    double acc = 0.0;
    for (int r0 = blockIdx.x * 2; r0 < N_NODES; r0 += KC_GRID * 2) {
        int row = r0 + half;                       // N even
        float wvv = w[row];
        float g = leaky(hp[(size_t)row * 128 + col]);
        acc += (double)(wvv * g);
    }
    __shared__ double sred[256];
    sred[t] = acc;
    __syncthreads();
    if (t < 128) hgpart[blockIdx.x * 128 + t] = sred[t] + sred[t + 128];
}

// ================= KD: reduce S/hg + full MLP in one block ============================
__global__ __launch_bounds__(1024) void kd_tail(
        const double* __restrict__ Spart, const double* __restrict__ hgpart,
        const float* __restrict__ W1, const float* __restrict__ b1,
        const float* __restrict__ W2, const float* __restrict__ b2,
        const float* __restrict__ W3, const float* __restrict__ b3,
        const float* __restrict__ W4, const float* __restrict__ b4,
        float* __restrict__ out) {
    __shared__ double dred[1024];
    __shared__ float fpart[1024];
    __shared__ float hgs[128];
    __shared__ float x1s[512];
    __shared__ float x2s[128];
    __shared__ float x3s[16];
    int t = threadIdx.x;

    dred[t] = Spart[t];                            // KB_GRID == 1024
    __syncthreads();
    for (int st = 512; st > 0; st >>= 1) {
        if (t < st) dred[t] += dred[t + st];
        __syncthreads();
    }
    double S = dred[0];
    __syncthreads();

    {   // hg
        int c = t & 127, g = t >> 7;
        double acc = 0.0;
        #pragma unroll 4
        for (int i = 0; i < 32; ++i)
            acc += hgpart[(size_t)(g * 32 + i) * 128 + c];
        dred[t] = acc;
        __syncthreads();
        if (t < 128) {
            double tot = 0.0;
            #pragma unroll
            for (int g2 = 0; g2 < 8; ++g2) tot += dred[t + 128 * g2];
            hgs[t] = (float)(tot / S);
        }
    }
    __syncthreads();

    {   // L1
        int o = t & 511, g = t >> 9;
        float acc = 0.f;
        #pragma unroll 8
        for (int i = 0; i < 64; ++i) {
            int d = g * 64 + i;
            acc += hgs[d] * W1[d * 512 + o];
        }
        fpart[t] = acc;
        __syncthreads();
        if (t < 512) x1s[t] = fmaxf(fpart[t] + fpart[t + 512] + b1[t], 0.f);
    }
    __syncthreads();

    {   // L2
        int o = t & 127, g = t >> 7;
        float acc = 0.f;
        #pragma unroll 8
        for (int i = 0; i < 64; ++i) {
            int k = g * 64 + i;
            acc += x1s[k] * W2[k * 128 + o];
        }
        fpart[t] = acc;
        __syncthreads();
        if (t < 128) {
            float s2 = b2[t];
            #pragma unroll
            for (int g2 = 0; g2 < 8; ++g2) s2 += fpart[t + 128 * g2];
            x2s[t] = fmaxf(s2, 0.f);
        }
    }
    __syncthreads();

    {   // L3
        if (t < 256) {
            int o = t & 15, g = t >> 4;
            float acc = 0.f;
            #pragma unroll
            for (int i = 0; i < 8; ++i) {
                int k = g * 8 + i;
                acc += x2s[k] * W3[k * 16 + o];
            }
            fpart[t] = acc;
        }
        __syncthreads();
        if (t < 16) {
            float s3 = b3[t];
            #pragma unroll
            for (int g2 = 0; g2 < 16; ++g2) s3 += fpart[t + 16 * g2];
            x3s[t] = fmaxf(s3, 0.f);
        }
    }
    __syncthreads();

    if (t == 0) {
        float acc = b4[0];
        #pragma unroll
        for (int k = 0; k < 16; ++k) acc += x3s[k] * W4[k];
        out[0] = acc;
    }
}

extern "C" void kernel_launch(void* const* d_in, const int* in_sizes, int n_in,
                              void* d_out, int out_size, void* d_ws, size_t ws_size,
                              hipStream_t stream) {
    const float* h   = (const float*)d_in[0];
    const float* e   = (const float*)d_in[1];
    const int*   src = (const int*)d_in[2];
    const int*   dst = (const int*)d_in[3];
    const float* W_u = (const float*)d_in[4];
    const float* W_e = (const float*)d_in[5];
    const float* a   = (const float*)d_in[6];
    const float* W_m = (const float*)d_in[7];
    const float* W1  = (const float*)d_in[8];
    const float* b1  = (const float*)d_in[9];
    const float* W2  = (const float*)d_in[10];
    const float* b2  = (const float*)d_in[11];
    const float* W3  = (const float*)d_in[12];
    const float* b3  = (const float*)d_in[13];
    const float* W4  = (const float*)d_in[14];
    const float* b4  = (const float*)d_in[15];
    float* out = (float*)d_out;

    char* ws = (char*)d_ws;
    float*  hp    = (float*)(ws);                     // 50000*128 f
    float*  ps    = (float*)(ws + 25600000);          // 50000 f
    float*  pd    = (float*)(ws + 25800000);          // 50000 f
    float*  w     = (float*)(ws + 26000000);          // 50000 f
    float*  dsc   = (float*)(ws + 26200000);          // 600000 f
    double* Spart = (double*)(ws + 28600000);         // 1024 d
    double* hgpart= (double*)(ws + 28608192);         // 256*128 d -> ends 28,870,336
    u16*    Bhi   = (u16*)(ws + 28870336);            // 16384 u16 = 32768 B
    u16*    Blo   = (u16*)(ws + 28903104);            // 32768 B -> ends 28,935,872

    hipLaunchKernelGGL(kp_pack, dim3(8), dim3(256), 0, stream, W_u, Bhi, Blo);
    hipLaunchKernelGGL(ka_fused, dim3(NB2 + NB1), dim3(256), 0, stream,
                       h, a, e, W_e, W_m, Bhi, Blo, hp, ps, pd, w, dsc);
    hipLaunchKernelGGL(kb_edge, dim3(KB_GRID), dim3(256), 0, stream,
                       src, dst, dsc, ps, pd, w, Spart);
    hipLaunchKernelGGL(kc_hg, dim3(KC_GRID), dim3(256), 0, stream, hp, w, hgpart);
    hipLaunchKernelGGL(kd_tail, dim3(1), dim3(1024), 0, stream,
                       Spart, hgpart, W1, b1, W2, b2, W3, b3, W4, b4, out);
}